// Round 6
// baseline (161.153 us; speedup 1.0000x reference)
//
#include <hip/hip_runtime.h>

#define NV   10
#define DD   2048
#define TAPS 25
#define GRP  64                 // channels per staged group
#define NG   (DD / GRP)         // 32 groups per o
#define GFL  (GRP * TAPS)       // 1600 floats = 6.4 KB per group
#define OB   64

typedef __attribute__((address_space(1))) const unsigned int gu32;
typedef __attribute__((address_space(3))) unsigned int lu32;

__device__ __forceinline__ float bsign(float v) {
    return (v > 0.0f) ? 1.0f : ((v < 0.0f) ? -1.0f : 0.0f);
}

// Stage one 64-channel group (1600 floats) of w[o] into this wave's private LDS
// buffer: 6 full + 1 16-lane global_load_lds width-16 => exactly 7 vmcnt ticks.
// Fully coalesced (wave reads 1KB contiguous per instr). Masked lanes don't
// write LDS (validated R3/R4).
__device__ __forceinline__ void stage(const float* __restrict__ gsrc,
                                      float* lbase, int lane) {
    #pragma unroll
    for (int i = 0; i < 6; ++i) {
        __builtin_amdgcn_global_load_lds((gu32*)(gsrc + 4 * (i * 64 + lane)),
                                         (lu32*)(lbase + 4 * (i * 64)), 16, 0, 0);
    }
    if (lane < 16) {
        __builtin_amdgcn_global_load_lds((gu32*)(gsrc + 4 * (384 + lane)),
                                         (lu32*)(lbase + 4 * 384), 16, 0, 0);
    }
}

// G[tap][n][o] = sum_c sign(values[n][c])*sign(w[o][c][tap]) via ballot+popcount.
// One o PER WAVE (4 per block). Wave-private double-buffered LDS staging paced
// by counted vmcnt(7): coalesced DMA loads + ZERO cross-wave sync in the loop.
__global__ __launch_bounds__(256) void g_kernel(
        const float* __restrict__ values,
        const float* __restrict__ w,
        float* __restrict__ G) {
    const int t    = threadIdx.x;
    const int lane = t & 63;
    const int wv   = t >> 6;
    const int o    = blockIdx.x * 4 + wv;

    __shared__ float buf[4][2][GFL];                // 51.2 KB: per-wave dbuf
    __shared__ unsigned long long s_vnz[NG * NV];   // [g][n]
    __shared__ unsigned long long s_vng[NG * NV];

    const float* wo = w + (size_t)o * (DD * TAPS);

    // get this wave's first group in flight immediately
    stage(wo, &buf[wv][0][0], lane);

    // value masks, cooperative (values = 80 KB, L2-hot); ballots overlap staging
    for (int t2 = wv; t2 < NG * NV; t2 += 4) {      // t2 wave-uniform
        const int g = t2 / NV;
        const int n = t2 - g * NV;
        float f = values[n * DD + g * 64 + lane];
        unsigned long long nz = __ballot(f != 0.0f);
        unsigned long long ng = __ballot(f < 0.0f);
        if (lane == 0) { s_vnz[g * NV + n] = nz; s_vng[g * NV + n] = ng; }
    }
    // publish masks WITHOUT draining vmcnt (keep group-0 loads in flight):
    asm volatile("s_waitcnt lgkmcnt(0)" ::: "memory");
    __builtin_amdgcn_s_barrier();

    int acc[TAPS];
    #pragma unroll
    for (int i = 0; i < TAPS; ++i) acc[i] = 0;

    for (int g = 0; g < NG; ++g) {
        // all ds_reads of the buffer that stage() is about to overwrite are done
        asm volatile("s_waitcnt lgkmcnt(0)" ::: "memory");
        if (g + 1 < NG) {
            stage(wo + (size_t)(g + 1) * GFL, &buf[wv][(g + 1) & 1][0], lane);
            // wait for current group's 7 loads; leave next group's 7 in flight
            asm volatile("s_waitcnt vmcnt(7)" ::: "memory");
        } else {
            asm volatile("s_waitcnt vmcnt(0)" ::: "memory");
        }
        __builtin_amdgcn_sched_barrier(0);

        const float* cb = &buf[wv][g & 1][0];
        unsigned long long vz = 0ull, vg = 0ull;
        if (lane < NV) {                             // lane = n for the accumulate
            vz = s_vnz[g * NV + lane];
            vg = s_vng[g * NV + lane];
        }
        #pragma unroll
        for (int tap = 0; tap < TAPS; ++tap) {
            // lane = channel-in-group; stride-25 words: 2 lanes/bank = conflict-free
            float f = cb[lane * TAPS + tap];
            unsigned long long wng = __ballot(f < 0.0f);
            unsigned long long wnz = __ballot(f != 0.0f);   // wave-uniform results
            unsigned long long nzb = wnz & vz;
            // exact: S += popc(bothnz) - 2*popc(signdiff & bothnz); zeros handled
            acc[tap] += (int)__popcll(nzb) - 2 * (int)__popcll((wng ^ vg) & nzb);
        }
    }

    if (lane < NV) {
        #pragma unroll
        for (int tap = 0; tap < TAPS; ++tap) {
            G[((size_t)(tap * NV + lane) << 11) + o] = (float)acc[tap];
        }
    }
}

// out[b,o,oh,ow] = sign(sum_tap G[idx(tap)][o][tap] + bias[o])
// tap-sum is an exact integer in f32; bias added ONCE at the end (bit-exact sign).
__global__ __launch_bounds__(256) void out_kernel(
        const float* __restrict__ x,
        const float* __restrict__ G,
        const float* __restrict__ bias,
        float* __restrict__ out) {
    const int bb    = blockIdx.x;
    const int half  = bb & 1;
    const int bq    = bb >> 1;
    const int b     = bq >> 5;
    const int oc    = bq & 31;
    const int obase = oc * OB;
    const int t     = threadIdx.x;

    __shared__ int   s_idx[28 * 28];
    __shared__ float s_out[OB * 73];     // [o_l][pos_local], odd stride: conflict-free

    for (int e = t; e < 28 * 28; e += 256) {
        s_idx[e] = (int)(x[b * 784 + e] * 9.0f);   // trunc, matches .astype(int32)
    }
    __syncthreads();

    const int o_l = t & (OB - 1);
    const int pg  = t >> 6;
    const float bv = bias[obase + o_l];
    const float* Gb = G + obase + o_l;

    for (int p0 = 0; p0 < 72; p0 += 4) {
        const int pos = half * 72 + p0 + pg;
        const int oh  = pos / 12;
        const int ow  = pos - oh * 12;
        float acc = 0.0f;                              // integer-exact accumulation
        #pragma unroll
        for (int kh = 0; kh < 5; ++kh) {
            const int row = (oh * 2 + kh) * 28 + ow * 2;
            #pragma unroll
            for (int kw = 0; kw < 5; ++kw) {
                const int nn = s_idx[row + kw];            // wave-uniform broadcast
                const int tp = kh * 5 + kw;
                acc += Gb[(size_t)(tp * NV + nn) << 11];   // coalesced, L2-hit
            }
        }
        s_out[o_l * 73 + p0 + pg] = bsign(acc + bv);
    }
    __syncthreads();

    float* dst = out + ((size_t)(b * DD + obase)) * 144;
    for (int e = t; e < OB * 72; e += 256) {
        const int ol = e / 72;
        const int pp = e - ol * 72;
        dst[ol * 144 + half * 72 + pp] = s_out[ol * 73 + pp];
    }
}

extern "C" void kernel_launch(void* const* d_in, const int* in_sizes, int n_in,
                              void* d_out, int out_size, void* d_ws, size_t ws_size,
                              hipStream_t stream) {
    const float* x      = (const float*)d_in[0];   // [16,1,28,28]
    const float* values = (const float*)d_in[1];   // [10,2048]
    const float* w      = (const float*)d_in[2];   // [2048,2048,5,5] OIHW
    const float* bias   = (const float*)d_in[3];   // [2048]
    float* out = (float*)d_out;                    // [16,2048,12,12]
    float* G   = (float*)d_ws;                     // 25*10*2048 floats = 2 MB scratch

    hipLaunchKernelGGL(g_kernel, dim3(DD / 4), dim3(256), 0, stream, values, w, G);
    hipLaunchKernelGGL(out_kernel, dim3(16 * (DD / OB) * 2), dim3(256), 0, stream, x, G, bias, out);
}